// Round 3
// baseline (227.550 us; speedup 1.0000x reference)
//
#include <hip/hip_runtime.h>
#include <stdint.h>
#include <stddef.h>

#define EMB 1024
#define NTOK 16384

typedef __attribute__((ext_vector_type(8))) short short8;
typedef __attribute__((ext_vector_type(4))) float floatx4;

__device__ __forceinline__ unsigned short f2bf(float f) {
    union { float f; unsigned int u; } v; v.f = f;
    unsigned int u = v.u;
    unsigned int r = (u + 0x7fffu + ((u >> 16) & 1u)) >> 16;
    return (unsigned short)r;
}
__device__ __forceinline__ float bf2f(unsigned short s) {
    union { unsigned int u; float f; } v; v.u = ((unsigned int)s) << 16;
    return v.f;
}

__device__ __forceinline__ void gload16(const void* g, void* l) {
    __builtin_amdgcn_global_load_lds(
        (const __attribute__((address_space(1))) void*)g,
        (__attribute__((address_space(3))) void*)l, 16, 0, 0);
}

// ---------------- fp32 -> bf16 conversion ----------------
__global__ void cvt_kernel(const float* __restrict__ in,
                           unsigned short* __restrict__ out, int n4) {
    int idx = blockIdx.x * blockDim.x + threadIdx.x;
    int stride = gridDim.x * blockDim.x;
    for (int i = idx; i < n4; i += stride) {
        float4 f = reinterpret_cast<const float4*>(in)[i];
        ushort4 o;
        o.x = f2bf(f.x); o.y = f2bf(f.y); o.z = f2bf(f.z); o.w = f2bf(f.w);
        reinterpret_cast<ushort4*>(out)[i] = o;
    }
}

// all 4 weight matrices in one dispatch; dst contiguous (Wq|Wk|Wv|Wo), each 2^18 float4s
__global__ void cvt4_kernel(const float* __restrict__ s0, const float* __restrict__ s1,
                            const float* __restrict__ s2, const float* __restrict__ s3,
                            unsigned short* __restrict__ out) {
    int idx = blockIdx.x * blockDim.x + threadIdx.x;
    const int total = 4 << 18;
    int stride = gridDim.x * blockDim.x;
    for (int i = idx; i < total; i += stride) {
        int w = i >> 18, r = i & ((1 << 18) - 1);
        const float* s = (w == 0) ? s0 : (w == 1) ? s1 : (w == 2) ? s2 : s3;
        float4 f = reinterpret_cast<const float4*>(s)[r];
        ushort4 o;
        o.x = f2bf(f.x); o.y = f2bf(f.y); o.z = f2bf(f.z); o.w = f2bf(f.w);
        reinterpret_cast<ushort4*>(out)[i] = o;
    }
}

__global__ void bias_cat_kernel(const float* __restrict__ b0,
                                const float* __restrict__ b1,
                                const float* __restrict__ b2,
                                float* __restrict__ out) {
    int i = blockIdx.x * blockDim.x + threadIdx.x;
    float v = (i < 1024) ? b0[i] : (i < 2048 ? b1[i - 1024] : b2[i - 2048]);
    out[i] = v;
}

// ---------------- 256x256 4-phase pipelined bf16 GEMM:  C = A*B^T + bias ----------------
// BK=64, 512 threads (8 waves 2Mx4N), LDS 128 KB double-buffered.
// Regions (ushort elems, per buffer b = t&1, base = b*32768):
//   A-kh0: +0      A-kh1: +8192    B-kh0: +16384   B-kh1: +24576
// 16B k-slots XOR-swizzled by ((row>>1)&3) on the GLOBAL source + LDS read addr.
// Fragment ds_reads are issued ONE PHASE AHEAD of their consuming MFMA cluster, so
// the DS pipe overlaps the matrix pipe. vmcnt(4) at phases 1 & 3 followed by a
// barrier makes cross-wave global_load_lds results visible before dependent reads.
__device__ __forceinline__ void store_val(float* C, size_t idx, float v) { C[idx] = v; }
__device__ __forceinline__ void store_val(unsigned short* C, size_t idx, float v) { C[idx] = f2bf(v); }

template<typename OUT_T>
__global__ __launch_bounds__(512, 2)
void gemm256(const unsigned short* __restrict__ A,
             const unsigned short* __restrict__ B,
             const float* __restrict__ bias,
             OUT_T* __restrict__ C,
             int K, int Nc, int grid_m)
{
    __shared__ unsigned short lds[65536];  // 128 KB

    const int bid = blockIdx.x;
    const int cpx = gridDim.x >> 3;
    const int wg  = (bid & 7) * cpx + (bid >> 3);
    const int m0 = (wg % grid_m) * 256;
    const int n0 = (wg / grid_m) * 256;

    const int tid  = threadIdx.x;
    const int lane = tid & 63;
    const int wid  = tid >> 6;
    const int wm = (wid >> 2) * 128;
    const int wn = (wid & 3) * 64;
    const int rr = lane & 15;
    const int klo = (((lane >> 4) ^ ((rr >> 1) & 3)) << 3);

    const unsigned short* pA[2];
    const unsigned short* pB[2];
    int ldst[2];
#pragma unroll
    for (int l = 0; l < 2; ++l) {
        const int P16  = l * 512 + tid;
        const int rowS = P16 >> 2;
        const int colel = (((P16 & 3) ^ ((rowS >> 1) & 3)) << 3);
        pA[l] = A + (size_t)(m0 + rowS) * K + colel;
        pB[l] = B + (size_t)(n0 + rowS) * K + colel;
        ldst[l] = P16 * 8;
    }

    floatx4 acc[8][4];
#pragma unroll
    for (int i = 0; i < 8; ++i)
#pragma unroll
        for (int j = 0; j < 4; ++j)
            acc[i][j] = (floatx4){0.f, 0.f, 0.f, 0.f};

    const int NT = K >> 6;

    // ---- prologue: stage tile 0 into buf0, drain, read phase-0 frags ----
#pragma unroll
    for (int l = 0; l < 2; ++l) {
        gload16(pA[l],      &lds[0     + ldst[l]]);
        gload16(pA[l] + 32, &lds[8192  + ldst[l]]);
        gload16(pB[l],      &lds[16384 + ldst[l]]);
        gload16(pB[l] + 32, &lds[24576 + ldst[l]]);
    }
    asm volatile("s_waitcnt vmcnt(0)" ::: "memory");
    asm volatile("s_barrier" ::: "memory");

    short8 afA[4], afB[4], bfA[4], bfB[4];
#pragma unroll
    for (int i = 0; i < 4; ++i)
        afA[i] = *reinterpret_cast<const short8*>(&lds[(wm + i * 16 + rr) * 32 + klo]);
#pragma unroll
    for (int j = 0; j < 4; ++j)
        bfA[j] = *reinterpret_cast<const short8*>(&lds[16384 + (wn + j * 16 + rr) * 32 + klo]);

    for (int t = 0; t < NT; ++t) {
        const int cur = (t & 1) * 32768;
        const int nxt = cur ^ 32768;
        const int ktn = (t + 1 < NT) ? (t + 1) * 64 : 0;

        // ===== phase 0: MFMA(kh0, rh0) ; read-ahead af(kh0, rh1) =====
        gload16(pA[0] + ktn, &lds[nxt + ldst[0]]);          // R0 = A-kh0(next)
        gload16(pA[1] + ktn, &lds[nxt + ldst[1]]);
#pragma unroll
        for (int i = 0; i < 4; ++i)
            afB[i] = *reinterpret_cast<const short8*>(&lds[cur + (wm + 64 + i * 16 + rr) * 32 + klo]);
        asm volatile("s_barrier" ::: "memory");
        __builtin_amdgcn_s_setprio(1);
#pragma unroll
        for (int j = 0; j < 4; ++j)
#pragma unroll
            for (int i = 0; i < 4; ++i)
                acc[i][j] = __builtin_amdgcn_mfma_f32_16x16x32_bf16(afA[i], bfA[j], acc[i][j], 0, 0, 0);
        __builtin_amdgcn_s_setprio(0);
        asm volatile("s_barrier" ::: "memory");

        // ===== phase 1: MFMA(kh0, rh1) ; read-ahead af(kh1, rh0) + bf(kh1) =====
        gload16(pB[0] + ktn, &lds[nxt + 16384 + ldst[0]]);  // R1 = B-kh0(next)
        gload16(pB[1] + ktn, &lds[nxt + 16384 + ldst[1]]);
        // drain R2,R3 of current tile (issued last tile); leaves R0,R1(next) in flight
        asm volatile("s_waitcnt vmcnt(4)" ::: "memory");
        asm volatile("s_barrier" ::: "memory");
#pragma unroll
        for (int i = 0; i < 4; ++i)
            afA[i] = *reinterpret_cast<const short8*>(&lds[cur + 8192 + (wm + i * 16 + rr) * 32 + klo]);
#pragma unroll
        for (int j = 0; j < 4; ++j)
            bfB[j] = *reinterpret_cast<const short8*>(&lds[cur + 24576 + (wn + j * 16 + rr) * 32 + klo]);
        __builtin_amdgcn_s_setprio(1);
#pragma unroll
        for (int j = 0; j < 4; ++j)
#pragma unroll
            for (int i = 0; i < 4; ++i)
                acc[4 + i][j] = __builtin_amdgcn_mfma_f32_16x16x32_bf16(afB[i], bfA[j], acc[4 + i][j], 0, 0, 0);
        __builtin_amdgcn_s_setprio(0);
        asm volatile("s_barrier" ::: "memory");

        // ===== phase 2: MFMA(kh1, rh0) ; read-ahead af(kh1, rh1) =====
        gload16(pA[0] + ktn + 32, &lds[nxt + 8192 + ldst[0]]);   // R2 = A-kh1(next)
        gload16(pA[1] + ktn + 32, &lds[nxt + 8192 + ldst[1]]);
#pragma unroll
        for (int i = 0; i < 4; ++i)
            afB[i] = *reinterpret_cast<const short8*>(&lds[cur + 8192 + (wm + 64 + i * 16 + rr) * 32 + klo]);
        asm volatile("s_barrier" ::: "memory");
        __builtin_amdgcn_s_setprio(1);
#pragma unroll
        for (int j = 0; j < 4; ++j)
#pragma unroll
            for (int i = 0; i < 4; ++i)
                acc[i][j] = __builtin_amdgcn_mfma_f32_16x16x32_bf16(afA[i], bfB[j], acc[i][j], 0, 0, 0);
        __builtin_amdgcn_s_setprio(0);
        asm volatile("s_barrier" ::: "memory");

        // ===== phase 3: MFMA(kh1, rh1) ; read-ahead next tile's (kh0, rh0)+bf(kh0) =====
        gload16(pB[0] + ktn + 32, &lds[nxt + 24576 + ldst[0]]);  // R3 = B-kh1(next)
        gload16(pB[1] + ktn + 32, &lds[nxt + 24576 + ldst[1]]);
        // drain R0,R1(next); leaves R2,R3(next) in flight
        asm volatile("s_waitcnt vmcnt(4)" ::: "memory");
        asm volatile("s_barrier" ::: "memory");
#pragma unroll
        for (int i = 0; i < 4; ++i)
            afA[i] = *reinterpret_cast<const short8*>(&lds[nxt + (wm + i * 16 + rr) * 32 + klo]);
#pragma unroll
        for (int j = 0; j < 4; ++j)
            bfA[j] = *reinterpret_cast<const short8*>(&lds[nxt + 16384 + (wn + j * 16 + rr) * 32 + klo]);
        __builtin_amdgcn_s_setprio(1);
#pragma unroll
        for (int j = 0; j < 4; ++j)
#pragma unroll
            for (int i = 0; i < 4; ++i)
                acc[4 + i][j] = __builtin_amdgcn_mfma_f32_16x16x32_bf16(afB[i], bfB[j], acc[4 + i][j], 0, 0, 0);
        __builtin_amdgcn_s_setprio(0);
        asm volatile("s_barrier" ::: "memory");
    }

    // ---- epilogue ----
    const int cn  = lane & 15;
    const int cm4 = (lane >> 4) * 4;
    float bv[4];
#pragma unroll
    for (int j = 0; j < 4; ++j) bv[j] = bias[n0 + wn + j * 16 + cn];
#pragma unroll
    for (int ai = 0; ai < 8; ++ai) {
        const int row = m0 + wm + (ai >> 2) * 64 + (ai & 3) * 16 + cm4;
#pragma unroll
        for (int j = 0; j < 4; ++j) {
            const int col = n0 + wn + j * 16 + cn;
#pragma unroll
            for (int r = 0; r < 4; ++r)
                store_val(C, (size_t)(row + r) * Nc + col, acc[ai][j][r] + bv[j]);
        }
    }
}

// ---------------- per-token 16-head attention (wave per token) ----------------
#define ROWP 72

__global__ __launch_bounds__(256)
void attn_kernel(const unsigned short* __restrict__ QKV,
                 unsigned short* __restrict__ O)
{
    const int wave = threadIdx.x >> 6;
    const int lane = threadIdx.x & 63;
    const int n = blockIdx.x * 4 + wave;

    __shared__ unsigned short lq[4][16 * ROWP];
    __shared__ unsigned short lk[4][16 * ROWP];
    __shared__ unsigned short lv[4][16 * ROWP];
    __shared__ float lp[4][256];

    {
        const unsigned short* gq = QKV + (size_t)n * 3072;
        const unsigned short* gk = gq + 1024;
        const unsigned short* gv = gq + 2048;
        for (int t = lane; t < 128; t += 64) {
            int r = t >> 3, c = t & 7;
            *reinterpret_cast<short8*>(&lq[wave][r * ROWP + c * 8]) =
                *reinterpret_cast<const short8*>(gq + t * 8);
            *reinterpret_cast<short8*>(&lk[wave][r * ROWP + c * 8]) =
                *reinterpret_cast<const short8*>(gk + t * 8);
            *reinterpret_cast<short8*>(&lv[wave][r * ROWP + c * 8]) =
                *reinterpret_cast<const short8*>(gv + t * 8);
        }
    }
    __syncthreads();

    const int g = lane & 15;
    const int a = lane >> 4;

    float kf[64];
#pragma unroll
    for (int c2 = 0; c2 < 8; ++c2) {
        short8 kv = *reinterpret_cast<const short8*>(&lk[wave][g * ROWP + c2 * 8]);
#pragma unroll
        for (int e = 0; e < 8; ++e) kf[c2 * 8 + e] = bf2f((unsigned short)kv[e]);
    }

#pragma unroll
    for (int i = 0; i < 4; ++i) {
        const int h = i * 4 + a;
        float s = 0.f;
#pragma unroll
        for (int c2 = 0; c2 < 8; ++c2) {
            short8 qv = *reinterpret_cast<const short8*>(&lq[wave][h * ROWP + c2 * 8]);
#pragma unroll
            for (int e = 0; e < 8; ++e)
                s = fmaf(bf2f((unsigned short)qv[e]), kf[c2 * 8 + e], s);
        }
        s *= 0.125f;

        float m = s;
#pragma unroll
        for (int o = 1; o < 16; o <<= 1) m = fmaxf(m, __shfl_xor(m, o, 64));
        float p = expf(s - m);
        float sum = p;
#pragma unroll
        for (int o = 1; o < 16; o <<= 1) sum += __shfl_xor(sum, o, 64);
        lp[wave][h * 16 + g] = p / sum;
    }
    __syncthreads();

    const int h = lane >> 2;
    const int db = (lane & 3) * 16;
    float o[16];
#pragma unroll
    for (int e = 0; e < 16; ++e) o[e] = 0.f;

    for (int g2 = 0; g2 < 16; ++g2) {
        const float pw = lp[wave][h * 16 + g2];
        short8 v0 = *reinterpret_cast<const short8*>(&lv[wave][g2 * ROWP + db]);
        short8 v1 = *reinterpret_cast<const short8*>(&lv[wave][g2 * ROWP + db + 8]);
#pragma unroll
        for (int e = 0; e < 8; ++e) {
            o[e]     = fmaf(pw, bf2f((unsigned short)v0[e]), o[e]);
            o[8 + e] = fmaf(pw, bf2f((unsigned short)v1[e]), o[8 + e]);
        }
    }

    short8 o0, o1;
#pragma unroll
    for (int e = 0; e < 8; ++e) {
        o0[e] = (short)f2bf(o[e]);
        o1[e] = (short)f2bf(o[8 + e]);
    }
    unsigned short* dst = O + (size_t)n * EMB + h * 64 + db;
    *reinterpret_cast<short8*>(dst) = o0;
    *reinterpret_cast<short8*>(dst + 8) = o1;
}

// ---------------- launch ----------------
extern "C" void kernel_launch(void* const* d_in, const int* in_sizes, int n_in,
                              void* d_out, int out_size, void* d_ws, size_t ws_size,
                              hipStream_t stream)
{
    const float* src = (const float*)d_in[0];
    const float* Wq  = (const float*)d_in[1];
    const float* bq  = (const float*)d_in[2];
    const float* Wk  = (const float*)d_in[3];
    const float* bk  = (const float*)d_in[4];
    const float* Wv  = (const float*)d_in[5];
    const float* bv  = (const float*)d_in[6];
    const float* Wo  = (const float*)d_in[7];
    const float* bo  = (const float*)d_in[8];
    float* out = (float*)d_out;

    unsigned short* ws = (unsigned short*)d_ws;
    unsigned short* src_bf = ws;                                      // 16384*1024
    unsigned short* wqkv   = src_bf + (size_t)NTOK * EMB;             // 3*1024*1024 (Wq|Wk|Wv)
    unsigned short* wo_bf  = wqkv + (size_t)3 * EMB * EMB;            // 1024*1024 (contiguous after wqkv)
    unsigned short* qkv    = wo_bf + (size_t)EMB * EMB;               // 16384*3072
    unsigned short* ab     = qkv + (size_t)NTOK * 3 * EMB;            // 16384*1024
    float* bias_cat        = (float*)(ab + (size_t)NTOK * EMB);       // 3072 floats

    cvt_kernel<<<2048, 256, 0, stream>>>(src, src_bf, NTOK * EMB / 4);
    cvt4_kernel<<<2048, 256, 0, stream>>>(Wq, Wk, Wv, Wo, wqkv);  // fills wqkv then wo_bf
    bias_cat_kernel<<<12, 256, 0, stream>>>(bq, bk, bv, bias_cat);

    // fused QKV projection: [16384][3072] = src_bf * [3072][1024]^T
    gemm256<unsigned short><<<dim3(64 * 12), 512, 0, stream>>>(
        src_bf, wqkv, bias_cat, qkv, EMB, 3 * EMB, 64);

    attn_kernel<<<NTOK / 4, 256, 0, stream>>>(qkv, ab);

    // output projection: [16384][1024]
    gemm256<float><<<dim3(64 * 4), 512, 0, stream>>>(
        ab, wo_bf, bo, out, EMB, EMB, 64);
}

// Round 4
// 208.905 us; speedup vs baseline: 1.0893x; 1.0893x over previous
//
#include <hip/hip_runtime.h>
#include <stdint.h>
#include <stddef.h>

#define EMB 1024
#define NTOK 16384

typedef __attribute__((ext_vector_type(8))) short short8;
typedef __attribute__((ext_vector_type(4))) float floatx4;

__device__ __forceinline__ unsigned short f2bf(float f) {
    union { float f; unsigned int u; } v; v.f = f;
    unsigned int u = v.u;
    unsigned int r = (u + 0x7fffu + ((u >> 16) & 1u)) >> 16;
    return (unsigned short)r;
}
__device__ __forceinline__ float bf2f(unsigned short s) {
    union { unsigned int u; float f; } v; v.u = ((unsigned int)s) << 16;
    return v.f;
}

__device__ __forceinline__ void gload16(const void* g, void* l) {
    __builtin_amdgcn_global_load_lds(
        (const __attribute__((address_space(1))) void*)g,
        (__attribute__((address_space(3))) void*)l, 16, 0, 0);
}

// ---------------- fp32 -> bf16 conversion ----------------
__global__ void cvt_kernel(const float* __restrict__ in,
                           unsigned short* __restrict__ out, int n4) {
    int idx = blockIdx.x * blockDim.x + threadIdx.x;
    int stride = gridDim.x * blockDim.x;
    for (int i = idx; i < n4; i += stride) {
        float4 f = reinterpret_cast<const float4*>(in)[i];
        ushort4 o;
        o.x = f2bf(f.x); o.y = f2bf(f.y); o.z = f2bf(f.z); o.w = f2bf(f.w);
        reinterpret_cast<ushort4*>(out)[i] = o;
    }
}

__global__ void cvt4_kernel(const float* __restrict__ s0, const float* __restrict__ s1,
                            const float* __restrict__ s2, const float* __restrict__ s3,
                            unsigned short* __restrict__ out) {
    int idx = blockIdx.x * blockDim.x + threadIdx.x;
    const int total = 4 << 18;
    int stride = gridDim.x * blockDim.x;
    for (int i = idx; i < total; i += stride) {
        int w = i >> 18, r = i & ((1 << 18) - 1);
        const float* s = (w == 0) ? s0 : (w == 1) ? s1 : (w == 2) ? s2 : s3;
        float4 f = reinterpret_cast<const float4*>(s)[r];
        ushort4 o;
        o.x = f2bf(f.x); o.y = f2bf(f.y); o.z = f2bf(f.z); o.w = f2bf(f.w);
        reinterpret_cast<ushort4*>(out)[i] = o;
    }
}

__global__ void bias_cat_kernel(const float* __restrict__ b0,
                                const float* __restrict__ b1,
                                const float* __restrict__ b2,
                                float* __restrict__ out) {
    int i = blockIdx.x * blockDim.x + threadIdx.x;
    float v = (i < 1024) ? b0[i] : (i < 2048 ? b1[i - 1024] : b2[i - 2048]);
    out[i] = v;
}

// ---------------- 256x256 bf16 GEMM, 2 sync points per K-tile ----------------
// BK=64, 512 threads (8 waves 2Mx4N), LDS 128 KB double-buffered.
// Regions (ushort elems, buffer base b*32768):
//   A-kh0: +0   A-kh1: +8192   B-kh0: +16384   B-kh1: +24576
// 16B k-slots XOR-swizzled by ((row>>1)&3) on GLOBAL source + LDS read addr.
// Per K-tile only TWO {vmcnt(4); s_barrier} sync points (after kh0 MFMAs and
// after kh1 MFMAs). Within each region, {gloads, ds_reads, 32 MFMAs} have only
// register deps -> compiler schedules lgkmcnt finely, waves slip, DS/MFMA/VMEM
// pipes overlap at CU level. Per-wave vmcnt is workgroup-valid because every
// wave executes it before the immediately following barrier.
__device__ __forceinline__ void store_val(float* C, size_t idx, float v) { C[idx] = v; }
__device__ __forceinline__ void store_val(unsigned short* C, size_t idx, float v) { C[idx] = f2bf(v); }

template<typename OUT_T>
__global__ __launch_bounds__(512, 2)
void gemm256(const unsigned short* __restrict__ A,
             const unsigned short* __restrict__ B,
             const float* __restrict__ bias,
             OUT_T* __restrict__ C,
             int K, int Nc, int grid_m)
{
    __shared__ unsigned short lds[65536];  // 128 KB

    const int bid = blockIdx.x;
    const int cpx = gridDim.x >> 3;
    const int wg  = (bid & 7) * cpx + (bid >> 3);
    const int m0 = (wg % grid_m) * 256;
    const int n0 = (wg / grid_m) * 256;

    const int tid  = threadIdx.x;
    const int lane = tid & 63;
    const int wid  = tid >> 6;
    const int wm = (wid >> 2) * 128;
    const int wn = (wid & 3) * 64;
    const int rr = lane & 15;
    const int klo = (((lane >> 4) ^ ((rr >> 1) & 3)) << 3);

    // LDS fragment read bases (elements); +i*512 walks 16-row groups,
    // +2048 = rh1 (+64 rows), +8192 = kh1 region.
    const int aro = (wm + rr) * 32 + klo;
    const int bro = 16384 + (wn + rr) * 32 + klo;

    const unsigned short* pA[2];
    const unsigned short* pB[2];
    int ldst[2];
#pragma unroll
    for (int l = 0; l < 2; ++l) {
        const int P16  = l * 512 + tid;
        const int rowS = P16 >> 2;
        const int colel = (((P16 & 3) ^ ((rowS >> 1) & 3)) << 3);
        pA[l] = A + (size_t)(m0 + rowS) * K + colel;
        pB[l] = B + (size_t)(n0 + rowS) * K + colel;
        ldst[l] = P16 * 8;
    }

    floatx4 acc[8][4];
#pragma unroll
    for (int i = 0; i < 8; ++i)
#pragma unroll
        for (int j = 0; j < 4; ++j)
            acc[i][j] = (floatx4){0.f, 0.f, 0.f, 0.f};

    const int NT = K >> 6;

    // ---- prologue: stage tile 0 into buf0, drain, read kh0 frags ----
#pragma unroll
    for (int l = 0; l < 2; ++l) {
        gload16(pA[l],      &lds[0     + ldst[l]]);
        gload16(pA[l] + 32, &lds[8192  + ldst[l]]);
        gload16(pB[l],      &lds[16384 + ldst[l]]);
        gload16(pB[l] + 32, &lds[24576 + ldst[l]]);
    }
    asm volatile("s_waitcnt vmcnt(0)" ::: "memory");
    asm volatile("s_barrier" ::: "memory");

    short8 a0[4], a1[4], b0[4];
#pragma unroll
    for (int i = 0; i < 4; ++i)
        a0[i] = *reinterpret_cast<const short8*>(&lds[aro + i * 512]);
#pragma unroll
    for (int j = 0; j < 4; ++j)
        b0[j] = *reinterpret_cast<const short8*>(&lds[bro + j * 512]);

    for (int t = 0; t < NT; ++t) {
        const int cur = (t & 1) * 32768;
        const int nxt = cur ^ 32768;
        const int ktn = (t + 1 < NT) ? (t + 1) * 64 : 0;

        // ============ region 1: kh0 (a0,b0 already in regs) ============
        gload16(pA[0] + ktn, &lds[nxt + ldst[0]]);           // R0 = A-kh0(next)
        gload16(pA[1] + ktn, &lds[nxt + ldst[1]]);
        gload16(pB[0] + ktn, &lds[nxt + 16384 + ldst[0]]);   // R1 = B-kh0(next)
        gload16(pB[1] + ktn, &lds[nxt + 16384 + ldst[1]]);
#pragma unroll
        for (int i = 0; i < 4; ++i)                          // rh1 of kh0
            a1[i] = *reinterpret_cast<const short8*>(&lds[cur + aro + 2048 + i * 512]);
        __builtin_amdgcn_s_setprio(1);
#pragma unroll
        for (int j = 0; j < 4; ++j)
#pragma unroll
            for (int i = 0; i < 4; ++i)
                acc[i][j] = __builtin_amdgcn_mfma_f32_16x16x32_bf16(a0[i], b0[j], acc[i][j], 0, 0, 0);
#pragma unroll
        for (int j = 0; j < 4; ++j)
#pragma unroll
            for (int i = 0; i < 4; ++i)
                acc[4 + i][j] = __builtin_amdgcn_mfma_f32_16x16x32_bf16(a1[i], b0[j], acc[4 + i][j], 0, 0, 0);
        __builtin_amdgcn_s_setprio(0);
        // drain prev tile's R2,R3 (this tile's kh1 regions); leaves R0,R1 in flight
        asm volatile("s_waitcnt vmcnt(4)" ::: "memory");
        asm volatile("s_barrier" ::: "memory");

        // ============ region 2: kh1 ============
        gload16(pA[0] + ktn + 32, &lds[nxt + 8192 + ldst[0]]);   // R2 = A-kh1(next)
        gload16(pA[1] + ktn + 32, &lds[nxt + 8192 + ldst[1]]);
        gload16(pB[0] + ktn + 32, &lds[nxt + 24576 + ldst[0]]);  // R3 = B-kh1(next)
        gload16(pB[1] + ktn + 32, &lds[nxt + 24576 + ldst[1]]);
#pragma unroll
        for (int i = 0; i < 4; ++i)
            a0[i] = *reinterpret_cast<const short8*>(&lds[cur + 8192 + aro + i * 512]);
#pragma unroll
        for (int j = 0; j < 4; ++j)
            b0[j] = *reinterpret_cast<const short8*>(&lds[cur + 8192 + bro + j * 512]);
#pragma unroll
        for (int i = 0; i < 4; ++i)
            a1[i] = *reinterpret_cast<const short8*>(&lds[cur + 8192 + aro + 2048 + i * 512]);
        __builtin_amdgcn_s_setprio(1);
#pragma unroll
        for (int j = 0; j < 4; ++j)
#pragma unroll
            for (int i = 0; i < 4; ++i)
                acc[i][j] = __builtin_amdgcn_mfma_f32_16x16x32_bf16(a0[i], b0[j], acc[i][j], 0, 0, 0);
#pragma unroll
        for (int j = 0; j < 4; ++j)
#pragma unroll
            for (int i = 0; i < 4; ++i)
                acc[4 + i][j] = __builtin_amdgcn_mfma_f32_16x16x32_bf16(a1[i], b0[j], acc[4 + i][j], 0, 0, 0);
        __builtin_amdgcn_s_setprio(0);
        // drain this tile's R0,R1 (next tile's kh0 regions); leaves R2,R3 in flight
        asm volatile("s_waitcnt vmcnt(4)" ::: "memory");
        asm volatile("s_barrier" ::: "memory");
        // read-ahead next tile's kh0 fragments
#pragma unroll
        for (int i = 0; i < 4; ++i)
            a0[i] = *reinterpret_cast<const short8*>(&lds[nxt + aro + i * 512]);
#pragma unroll
        for (int j = 0; j < 4; ++j)
            b0[j] = *reinterpret_cast<const short8*>(&lds[nxt + bro + j * 512]);
    }

    // ---- epilogue ----
    const int cn  = lane & 15;
    const int cm4 = (lane >> 4) * 4;
    float bv[4];
#pragma unroll
    for (int j = 0; j < 4; ++j) bv[j] = bias[n0 + wn + j * 16 + cn];
#pragma unroll
    for (int ai = 0; ai < 8; ++ai) {
        const int row = m0 + wm + (ai >> 2) * 64 + (ai & 3) * 16 + cm4;
#pragma unroll
        for (int j = 0; j < 4; ++j) {
            const int col = n0 + wn + j * 16 + cn;
#pragma unroll
            for (int r = 0; r < 4; ++r)
                store_val(C, (size_t)(row + r) * Nc + col, acc[ai][j][r] + bv[j]);
        }
    }
}

// ---------------- per-token 16-head attention (wave per token) ----------------
#define ROWP 72

__global__ __launch_bounds__(256)
void attn_kernel(const unsigned short* __restrict__ QKV,
                 unsigned short* __restrict__ O)
{
    const int wave = threadIdx.x >> 6;
    const int lane = threadIdx.x & 63;
    const int n = blockIdx.x * 4 + wave;

    __shared__ unsigned short lq[4][16 * ROWP];
    __shared__ unsigned short lk[4][16 * ROWP];
    __shared__ unsigned short lv[4][16 * ROWP];
    __shared__ float lp[4][256];

    {
        const unsigned short* gq = QKV + (size_t)n * 3072;
        const unsigned short* gk = gq + 1024;
        const unsigned short* gv = gq + 2048;
        for (int t = lane; t < 128; t += 64) {
            int r = t >> 3, c = t & 7;
            *reinterpret_cast<short8*>(&lq[wave][r * ROWP + c * 8]) =
                *reinterpret_cast<const short8*>(gq + t * 8);
            *reinterpret_cast<short8*>(&lk[wave][r * ROWP + c * 8]) =
                *reinterpret_cast<const short8*>(gk + t * 8);
            *reinterpret_cast<short8*>(&lv[wave][r * ROWP + c * 8]) =
                *reinterpret_cast<const short8*>(gv + t * 8);
        }
    }
    __syncthreads();

    const int g = lane & 15;
    const int a = lane >> 4;

    float kf[64];
#pragma unroll
    for (int c2 = 0; c2 < 8; ++c2) {
        short8 kv = *reinterpret_cast<const short8*>(&lk[wave][g * ROWP + c2 * 8]);
#pragma unroll
        for (int e = 0; e < 8; ++e) kf[c2 * 8 + e] = bf2f((unsigned short)kv[e]);
    }

#pragma unroll
    for (int i = 0; i < 4; ++i) {
        const int h = i * 4 + a;
        float s = 0.f;
#pragma unroll
        for (int c2 = 0; c2 < 8; ++c2) {
            short8 qv = *reinterpret_cast<const short8*>(&lq[wave][h * ROWP + c2 * 8]);
#pragma unroll
            for (int e = 0; e < 8; ++e)
                s = fmaf(bf2f((unsigned short)qv[e]), kf[c2 * 8 + e], s);
        }
        s *= 0.125f;

        float m = s;
#pragma unroll
        for (int o = 1; o < 16; o <<= 1) m = fmaxf(m, __shfl_xor(m, o, 64));
        float p = expf(s - m);
        float sum = p;
#pragma unroll
        for (int o = 1; o < 16; o <<= 1) sum += __shfl_xor(sum, o, 64);
        lp[wave][h * 16 + g] = p / sum;
    }
    __syncthreads();

    const int h = lane >> 2;
    const int db = (lane & 3) * 16;
    float o[16];
#pragma unroll
    for (int e = 0; e < 16; ++e) o[e] = 0.f;

    for (int g2 = 0; g2 < 16; ++g2) {
        const float pw = lp[wave][h * 16 + g2];
        short8 v0 = *reinterpret_cast<const short8*>(&lv[wave][g2 * ROWP + db]);
        short8 v1 = *reinterpret_cast<const short8*>(&lv[wave][g2 * ROWP + db + 8]);
#pragma unroll
        for (int e = 0; e < 8; ++e) {
            o[e]     = fmaf(pw, bf2f((unsigned short)v0[e]), o[e]);
            o[8 + e] = fmaf(pw, bf2f((unsigned short)v1[e]), o[8 + e]);
        }
    }

    short8 o0, o1;
#pragma unroll
    for (int e = 0; e < 8; ++e) {
        o0[e] = (short)f2bf(o[e]);
        o1[e] = (short)f2bf(o[8 + e]);
    }
    unsigned short* dst = O + (size_t)n * EMB + h * 64 + db;
    *reinterpret_cast<short8*>(dst) = o0;
    *reinterpret_cast<short8*>(dst + 8) = o1;
}

// ---------------- launch ----------------
extern "C" void kernel_launch(void* const* d_in, const int* in_sizes, int n_in,
                              void* d_out, int out_size, void* d_ws, size_t ws_size,
                              hipStream_t stream)
{
    const float* src = (const float*)d_in[0];
    const float* Wq  = (const float*)d_in[1];
    const float* bq  = (const float*)d_in[2];
    const float* Wk  = (const float*)d_in[3];
    const float* bk  = (const float*)d_in[4];
    const float* Wv  = (const float*)d_in[5];
    const float* bv  = (const float*)d_in[6];
    const float* Wo  = (const float*)d_in[7];
    const float* bo  = (const float*)d_in[8];
    float* out = (float*)d_out;

    unsigned short* ws = (unsigned short*)d_ws;
    unsigned short* src_bf = ws;                                      // 16384*1024
    unsigned short* wqkv   = src_bf + (size_t)NTOK * EMB;             // 3*1024*1024 (Wq|Wk|Wv)
    unsigned short* wo_bf  = wqkv + (size_t)3 * EMB * EMB;            // 1024*1024 (contiguous after wqkv)
    unsigned short* qkv    = wo_bf + (size_t)EMB * EMB;               // 16384*3072
    unsigned short* ab     = qkv + (size_t)NTOK * 3 * EMB;            // 16384*1024
    float* bias_cat        = (float*)(ab + (size_t)NTOK * EMB);       // 3072 floats

    cvt_kernel<<<2048, 256, 0, stream>>>(src, src_bf, NTOK * EMB / 4);
    cvt4_kernel<<<2048, 256, 0, stream>>>(Wq, Wk, Wv, Wo, wqkv);  // fills wqkv then wo_bf
    bias_cat_kernel<<<12, 256, 0, stream>>>(bq, bk, bv, bias_cat);

    // fused QKV projection: [16384][3072] = src_bf * [3072][1024]^T
    gemm256<unsigned short><<<dim3(64 * 12), 512, 0, stream>>>(
        src_bf, wqkv, bias_cat, qkv, EMB, 3 * EMB, 64);

    attn_kernel<<<NTOK / 4, 256, 0, stream>>>(qkv, ab);

    // output projection: [16384][1024]
    gemm256<float><<<dim3(64 * 4), 512, 0, stream>>>(
        ab, wo_bf, bo, out, EMB, EMB, 64);
}

// Round 5
// 200.208 us; speedup vs baseline: 1.1366x; 1.0434x over previous
//
#include <hip/hip_runtime.h>
#include <stdint.h>
#include <stddef.h>

#define EMB 1024
#define NTOK 16384

typedef __attribute__((ext_vector_type(8))) short short8;
typedef __attribute__((ext_vector_type(4))) float floatx4;

__device__ __forceinline__ unsigned short f2bf(float f) {
    union { float f; unsigned int u; } v; v.f = f;
    unsigned int u = v.u;
    unsigned int r = (u + 0x7fffu + ((u >> 16) & 1u)) >> 16;
    return (unsigned short)r;
}
__device__ __forceinline__ float bf2f(unsigned short s) {
    union { unsigned int u; float f; } v; v.u = ((unsigned int)s) << 16;
    return v.f;
}

__device__ __forceinline__ void gload16(const void* g, void* l) {
    __builtin_amdgcn_global_load_lds(
        (const __attribute__((address_space(1))) void*)g,
        (__attribute__((address_space(3))) void*)l, 16, 0, 0);
}

// ---------------- fp32 -> bf16 conversion ----------------
__global__ void cvt_kernel(const float* __restrict__ in,
                           unsigned short* __restrict__ out, int n4) {
    int idx = blockIdx.x * blockDim.x + threadIdx.x;
    int stride = gridDim.x * blockDim.x;
    for (int i = idx; i < n4; i += stride) {
        float4 f = reinterpret_cast<const float4*>(in)[i];
        ushort4 o;
        o.x = f2bf(f.x); o.y = f2bf(f.y); o.z = f2bf(f.z); o.w = f2bf(f.w);
        reinterpret_cast<ushort4*>(out)[i] = o;
    }
}

__global__ void cvt4_kernel(const float* __restrict__ s0, const float* __restrict__ s1,
                            const float* __restrict__ s2, const float* __restrict__ s3,
                            unsigned short* __restrict__ out) {
    int idx = blockIdx.x * blockDim.x + threadIdx.x;
    const int total = 4 << 18;
    int stride = gridDim.x * blockDim.x;
    for (int i = idx; i < total; i += stride) {
        int w = i >> 18, r = i & ((1 << 18) - 1);
        const float* s = (w == 0) ? s0 : (w == 1) ? s1 : (w == 2) ? s2 : s3;
        float4 f = reinterpret_cast<const float4*>(s)[r];
        ushort4 o;
        o.x = f2bf(f.x); o.y = f2bf(f.y); o.z = f2bf(f.z); o.w = f2bf(f.w);
        reinterpret_cast<ushort4*>(out)[i] = o;
    }
}

__global__ void bias_cat_kernel(const float* __restrict__ b0,
                                const float* __restrict__ b1,
                                const float* __restrict__ b2,
                                float* __restrict__ out) {
    int i = blockIdx.x * blockDim.x + threadIdx.x;
    float v = (i < 1024) ? b0[i] : (i < 2048 ? b1[i - 1024] : b2[i - 2048]);
    out[i] = v;
}

// ---------------- 256x256 bf16 GEMM, 2 sync points per K-tile ----------------
// BK=64, 512 threads (8 waves 2Mx4N), LDS 128 KB double-buffered.
// Regions (ushort elems, buffer base b*32768):
//   A-kh0: +0   A-kh1: +8192   B-kh0: +16384   B-kh1: +24576
// 16B k-slots XOR-swizzled by ((row>>1)&3) on GLOBAL source + LDS read addr.
// Work-to-XCD mapping: each XCD owns an 8-m-tile stripe (A-stripe = 4 MB, fits
// its private 4 MB L2) and iterates n fastest -> A fetched ~once per XCD.
__device__ __forceinline__ void store_val(float* C, size_t idx, float v) { C[idx] = v; }
__device__ __forceinline__ void store_val(unsigned short* C, size_t idx, float v) { C[idx] = f2bf(v); }

template<typename OUT_T>
__global__ __launch_bounds__(512, 2)
void gemm256(const unsigned short* __restrict__ A,
             const unsigned short* __restrict__ B,
             const float* __restrict__ bias,
             OUT_T* __restrict__ C,
             int K, int Nc, int grid_m)
{
    __shared__ unsigned short lds[65536];  // 128 KB

    // XCD-stripe mapping: x = XCD, stripe of (grid_m/8) m-tiles per XCD, n fastest.
    const int bid = blockIdx.x;
    const int x = bid & 7;
    const int w = bid >> 3;
    const int ms = grid_m >> 3;                 // m-tiles per XCD stripe (8 here)
    const int m0 = (x * ms + (w & (ms - 1))) * 256;
    const int n0 = (w / ms) * 256;

    const int tid  = threadIdx.x;
    const int lane = tid & 63;
    const int wid  = tid >> 6;
    const int wm = (wid >> 2) * 128;
    const int wn = (wid & 3) * 64;
    const int rr = lane & 15;
    const int klo = (((lane >> 4) ^ ((rr >> 1) & 3)) << 3);

    const int aro = (wm + rr) * 32 + klo;
    const int bro = 16384 + (wn + rr) * 32 + klo;

    const unsigned short* pA[2];
    const unsigned short* pB[2];
    int ldst[2];
#pragma unroll
    for (int l = 0; l < 2; ++l) {
        const int P16  = l * 512 + tid;
        const int rowS = P16 >> 2;
        const int colel = (((P16 & 3) ^ ((rowS >> 1) & 3)) << 3);
        pA[l] = A + (size_t)(m0 + rowS) * K + colel;
        pB[l] = B + (size_t)(n0 + rowS) * K + colel;
        ldst[l] = P16 * 8;
    }

    floatx4 acc[8][4];
#pragma unroll
    for (int i = 0; i < 8; ++i)
#pragma unroll
        for (int j = 0; j < 4; ++j)
            acc[i][j] = (floatx4){0.f, 0.f, 0.f, 0.f};

    const int NT = K >> 6;

    // ---- prologue: stage tile 0 into buf0, drain, read kh0 frags ----
#pragma unroll
    for (int l = 0; l < 2; ++l) {
        gload16(pA[l],      &lds[0     + ldst[l]]);
        gload16(pA[l] + 32, &lds[8192  + ldst[l]]);
        gload16(pB[l],      &lds[16384 + ldst[l]]);
        gload16(pB[l] + 32, &lds[24576 + ldst[l]]);
    }
    asm volatile("s_waitcnt vmcnt(0)" ::: "memory");
    asm volatile("s_barrier" ::: "memory");

    short8 a0[4], a1[4], b0[4];
#pragma unroll
    for (int i = 0; i < 4; ++i)
        a0[i] = *reinterpret_cast<const short8*>(&lds[aro + i * 512]);
#pragma unroll
    for (int j = 0; j < 4; ++j)
        b0[j] = *reinterpret_cast<const short8*>(&lds[bro + j * 512]);

    for (int t = 0; t < NT; ++t) {
        const int cur = (t & 1) * 32768;
        const int nxt = cur ^ 32768;
        const int ktn = (t + 1 < NT) ? (t + 1) * 64 : 0;

        // ============ region 1: kh0 (a0,b0 already in regs) ============
        gload16(pA[0] + ktn, &lds[nxt + ldst[0]]);           // R0 = A-kh0(next)
        gload16(pA[1] + ktn, &lds[nxt + ldst[1]]);
        gload16(pB[0] + ktn, &lds[nxt + 16384 + ldst[0]]);   // R1 = B-kh0(next)
        gload16(pB[1] + ktn, &lds[nxt + 16384 + ldst[1]]);
#pragma unroll
        for (int i = 0; i < 4; ++i)                          // rh1 of kh0
            a1[i] = *reinterpret_cast<const short8*>(&lds[cur + aro + 2048 + i * 512]);
        __builtin_amdgcn_s_setprio(1);
#pragma unroll
        for (int j = 0; j < 4; ++j)
#pragma unroll
            for (int i = 0; i < 4; ++i)
                acc[i][j] = __builtin_amdgcn_mfma_f32_16x16x32_bf16(a0[i], b0[j], acc[i][j], 0, 0, 0);
#pragma unroll
        for (int j = 0; j < 4; ++j)
#pragma unroll
            for (int i = 0; i < 4; ++i)
                acc[4 + i][j] = __builtin_amdgcn_mfma_f32_16x16x32_bf16(a1[i], b0[j], acc[4 + i][j], 0, 0, 0);
        __builtin_amdgcn_s_setprio(0);
        // drain prev tile's R2,R3 (this tile's kh1 regions); leaves R0,R1 in flight
        asm volatile("s_waitcnt vmcnt(4)" ::: "memory");
        asm volatile("s_barrier" ::: "memory");

        // ============ region 2: kh1 ============
        gload16(pA[0] + ktn + 32, &lds[nxt + 8192 + ldst[0]]);   // R2 = A-kh1(next)
        gload16(pA[1] + ktn + 32, &lds[nxt + 8192 + ldst[1]]);
        gload16(pB[0] + ktn + 32, &lds[nxt + 24576 + ldst[0]]);  // R3 = B-kh1(next)
        gload16(pB[1] + ktn + 32, &lds[nxt + 24576 + ldst[1]]);
#pragma unroll
        for (int i = 0; i < 4; ++i)
            a0[i] = *reinterpret_cast<const short8*>(&lds[cur + 8192 + aro + i * 512]);
#pragma unroll
        for (int j = 0; j < 4; ++j)
            b0[j] = *reinterpret_cast<const short8*>(&lds[cur + 8192 + bro + j * 512]);
#pragma unroll
        for (int i = 0; i < 4; ++i)
            a1[i] = *reinterpret_cast<const short8*>(&lds[cur + 8192 + aro + 2048 + i * 512]);
        __builtin_amdgcn_s_setprio(1);
#pragma unroll
        for (int j = 0; j < 4; ++j)
#pragma unroll
            for (int i = 0; i < 4; ++i)
                acc[i][j] = __builtin_amdgcn_mfma_f32_16x16x32_bf16(a0[i], b0[j], acc[i][j], 0, 0, 0);
#pragma unroll
        for (int j = 0; j < 4; ++j)
#pragma unroll
            for (int i = 0; i < 4; ++i)
                acc[4 + i][j] = __builtin_amdgcn_mfma_f32_16x16x32_bf16(a1[i], b0[j], acc[4 + i][j], 0, 0, 0);
        __builtin_amdgcn_s_setprio(0);
        // drain this tile's R0,R1 (next tile's kh0 regions); leaves R2,R3 in flight
        asm volatile("s_waitcnt vmcnt(4)" ::: "memory");
        asm volatile("s_barrier" ::: "memory");
        // read-ahead next tile's kh0 fragments
#pragma unroll
        for (int i = 0; i < 4; ++i)
            a0[i] = *reinterpret_cast<const short8*>(&lds[nxt + aro + i * 512]);
#pragma unroll
        for (int j = 0; j < 4; ++j)
            b0[j] = *reinterpret_cast<const short8*>(&lds[nxt + bro + j * 512]);
    }

    // ---- epilogue ----
    const int cn  = lane & 15;
    const int cm4 = (lane >> 4) * 4;
    float bv[4];
#pragma unroll
    for (int j = 0; j < 4; ++j) bv[j] = bias[n0 + wn + j * 16 + cn];
#pragma unroll
    for (int ai = 0; ai < 8; ++ai) {
        const int row = m0 + wm + (ai >> 2) * 64 + (ai & 3) * 16 + cm4;
#pragma unroll
        for (int j = 0; j < 4; ++j) {
            const int col = n0 + wn + j * 16 + cn;
#pragma unroll
            for (int r = 0; r < 4; ++r)
                store_val(C, (size_t)(row + r) * Nc + col, acc[ai][j][r] + bv[j]);
        }
    }
}

// ---------------- per-token 16-head attention (wave per token) ----------------
#define ROWP 72

__global__ __launch_bounds__(256)
void attn_kernel(const unsigned short* __restrict__ QKV,
                 unsigned short* __restrict__ O)
{
    const int wave = threadIdx.x >> 6;
    const int lane = threadIdx.x & 63;
    const int n = blockIdx.x * 4 + wave;

    __shared__ unsigned short lq[4][16 * ROWP];
    __shared__ unsigned short lk[4][16 * ROWP];
    __shared__ unsigned short lv[4][16 * ROWP];
    __shared__ float lp[4][256];

    {
        const unsigned short* gq = QKV + (size_t)n * 3072;
        const unsigned short* gk = gq + 1024;
        const unsigned short* gv = gq + 2048;
        for (int t = lane; t < 128; t += 64) {
            int r = t >> 3, c = t & 7;
            *reinterpret_cast<short8*>(&lq[wave][r * ROWP + c * 8]) =
                *reinterpret_cast<const short8*>(gq + t * 8);
            *reinterpret_cast<short8*>(&lk[wave][r * ROWP + c * 8]) =
                *reinterpret_cast<const short8*>(gk + t * 8);
            *reinterpret_cast<short8*>(&lv[wave][r * ROWP + c * 8]) =
                *reinterpret_cast<const short8*>(gv + t * 8);
        }
    }
    __syncthreads();

    const int g = lane & 15;
    const int a = lane >> 4;

    float kf[64];
#pragma unroll
    for (int c2 = 0; c2 < 8; ++c2) {
        short8 kv = *reinterpret_cast<const short8*>(&lk[wave][g * ROWP + c2 * 8]);
#pragma unroll
        for (int e = 0; e < 8; ++e) kf[c2 * 8 + e] = bf2f((unsigned short)kv[e]);
    }

#pragma unroll
    for (int i = 0; i < 4; ++i) {
        const int h = i * 4 + a;
        float s = 0.f;
#pragma unroll
        for (int c2 = 0; c2 < 8; ++c2) {
            short8 qv = *reinterpret_cast<const short8*>(&lq[wave][h * ROWP + c2 * 8]);
#pragma unroll
            for (int e = 0; e < 8; ++e)
                s = fmaf(bf2f((unsigned short)qv[e]), kf[c2 * 8 + e], s);
        }
        s *= 0.125f;

        float m = s;
#pragma unroll
        for (int o = 1; o < 16; o <<= 1) m = fmaxf(m, __shfl_xor(m, o, 64));
        float p = expf(s - m);
        float sum = p;
#pragma unroll
        for (int o = 1; o < 16; o <<= 1) sum += __shfl_xor(sum, o, 64);
        lp[wave][h * 16 + g] = p / sum;
    }
    __syncthreads();

    const int h = lane >> 2;
    const int db = (lane & 3) * 16;
    float o[16];
#pragma unroll
    for (int e = 0; e < 16; ++e) o[e] = 0.f;

    for (int g2 = 0; g2 < 16; ++g2) {
        const float pw = lp[wave][h * 16 + g2];
        short8 v0 = *reinterpret_cast<const short8*>(&lv[wave][g2 * ROWP + db]);
        short8 v1 = *reinterpret_cast<const short8*>(&lv[wave][g2 * ROWP + db + 8]);
#pragma unroll
        for (int e = 0; e < 8; ++e) {
            o[e]     = fmaf(pw, bf2f((unsigned short)v0[e]), o[e]);
            o[8 + e] = fmaf(pw, bf2f((unsigned short)v1[e]), o[8 + e]);
        }
    }

    short8 o0, o1;
#pragma unroll
    for (int e = 0; e < 8; ++e) {
        o0[e] = (short)f2bf(o[e]);
        o1[e] = (short)f2bf(o[8 + e]);
    }
    unsigned short* dst = O + (size_t)n * EMB + h * 64 + db;
    *reinterpret_cast<short8*>(dst) = o0;
    *reinterpret_cast<short8*>(dst + 8) = o1;
}

// ---------------- launch ----------------
extern "C" void kernel_launch(void* const* d_in, const int* in_sizes, int n_in,
                              void* d_out, int out_size, void* d_ws, size_t ws_size,
                              hipStream_t stream)
{
    const float* src = (const float*)d_in[0];
    const float* Wq  = (const float*)d_in[1];
    const float* bq  = (const float*)d_in[2];
    const float* Wk  = (const float*)d_in[3];
    const float* bk  = (const float*)d_in[4];
    const float* Wv  = (const float*)d_in[5];
    const float* bv  = (const float*)d_in[6];
    const float* Wo  = (const float*)d_in[7];
    const float* bo  = (const float*)d_in[8];
    float* out = (float*)d_out;

    unsigned short* ws = (unsigned short*)d_ws;
    unsigned short* src_bf = ws;                                      // 16384*1024
    unsigned short* wqkv   = src_bf + (size_t)NTOK * EMB;             // 3*1024*1024 (Wq|Wk|Wv)
    unsigned short* wo_bf  = wqkv + (size_t)3 * EMB * EMB;            // 1024*1024 (contiguous after wqkv)
    unsigned short* qkv    = wo_bf + (size_t)EMB * EMB;               // 16384*3072
    unsigned short* ab     = qkv + (size_t)NTOK * 3 * EMB;            // 16384*1024
    float* bias_cat        = (float*)(ab + (size_t)NTOK * EMB);       // 3072 floats

    cvt_kernel<<<2048, 256, 0, stream>>>(src, src_bf, NTOK * EMB / 4);
    cvt4_kernel<<<2048, 256, 0, stream>>>(Wq, Wk, Wv, Wo, wqkv);  // fills wqkv then wo_bf
    bias_cat_kernel<<<12, 256, 0, stream>>>(bq, bk, bv, bias_cat);

    // fused QKV projection: [16384][3072] = src_bf * [3072][1024]^T
    gemm256<unsigned short><<<dim3(64 * 12), 512, 0, stream>>>(
        src_bf, wqkv, bias_cat, qkv, EMB, 3 * EMB, 64);

    attn_kernel<<<NTOK / 4, 256, 0, stream>>>(qkv, ab);

    // output projection: [16384][1024]
    gemm256<float><<<dim3(64 * 4), 512, 0, stream>>>(
        ab, wo_bf, bo, out, EMB, EMB, 64);
}